// Round 1
// baseline (2170.671 us; speedup 1.0000x reference)
//
#include <hip/hip_runtime.h>
#include <hip/hip_bf16.h>
#include <stdint.h>

#define IGNORE_INDEX (-100)

constexpr int Bb = 4, Ss = 2048, Dd = 2048, Vv = 32000;
constexpr int M_ = Bb * Ss;   // 8192 tokens
constexpr int K_ = Dd;        // 2048
constexpr int N_ = Vv;        // 32000 vocab

constexpr int BM = 128, BN = 128, BK = 32;
constexpr int LDA = BK + 8;   // padded LDS stride in bf16 elems (40 -> 80B rows, 2-way max conflict)

typedef __attribute__((ext_vector_type(8))) __bf16 bf16x8;
typedef __attribute__((ext_vector_type(4))) float f32x4;
typedef __attribute__((ext_vector_type(4))) unsigned int u32x4;

// pack two fp32 -> two bf16 (round-half-up via +0x8000, then grab top bytes with one v_perm)
__device__ __forceinline__ unsigned pack_bf16(float f0, float f1) {
    unsigned u0 = __builtin_bit_cast(unsigned, f0) + 0x8000u;
    unsigned u1 = __builtin_bit_cast(unsigned, f1) + 0x8000u;
    // concat = (src0 << 32) | src1 ; select bytes {7,6,3,2} -> [bf16(f1) : bf16(f0)]
    return __builtin_amdgcn_perm(u1, u0, 0x07060302u);
}

__device__ __forceinline__ u32x4 pack8(f32x4 lo, f32x4 hi) {
    u32x4 r;
    r[0] = pack_bf16(lo[0], lo[1]);
    r[1] = pack_bf16(lo[2], lo[3]);
    r[2] = pack_bf16(hi[0], hi[1]);
    r[3] = pack_bf16(hi[2], hi[3]);
    return r;
}

__global__ void init_acc(float* p, int n) {
    int i = blockIdx.x * 256 + threadIdx.x;
    if (i < n) p[i] = 0.0f;
}

// A: hidden [M,K] fp32 row-major; W: [N,K] fp32 row-major (K-contiguous both => BT-GEMM)
__global__ __launch_bounds__(256) void gemm_fused(
    const float* __restrict__ A,
    const float* __restrict__ W,
    const int*   __restrict__ tgt,
    float* __restrict__ sumexp,
    float* __restrict__ tgtlogit)
{
    __shared__ __bf16 As[BM * LDA];
    __shared__ __bf16 Bs[BN * LDA];
    __shared__ int    tg[BM];

    const int tid = threadIdx.x;
    const int mt  = blockIdx.x;   // 0..63  (fastest -> W column tile shared by adjacent blocks)
    const int nt  = blockIdx.y;   // 0..249

    if (tid < BM) tg[tid] = tgt[mt * BM + tid];

    const int wave  = tid >> 6;
    const int lane  = tid & 63;
    const int wm    = wave >> 1;      // 2x2 wave grid, each wave 64x64
    const int wn    = wave & 1;
    const int lquad = lane >> 4;
    const int lcol  = lane & 15;

    // staging: each thread stages 2 rows (r, r+64) x 8 consecutive floats for A and B
    const int srow = tid >> 2;          // 0..63
    const int scol = (tid & 3) * 8;     // 0,8,16,24

    const float* gA = A + (size_t)(mt * BM + srow) * K_ + scol;
    const float* gB = W + (size_t)(nt * BN + srow) * K_ + scol;
    const size_t rowstep = (size_t)64 * K_;

    f32x4 acc[4][4];
#pragma unroll
    for (int i = 0; i < 4; i++)
#pragma unroll
        for (int j = 0; j < 4; j++) acc[i][j] = (f32x4){0.f, 0.f, 0.f, 0.f};

    for (int kt = 0; kt < K_; kt += BK) {
        // global fp32 loads (coalesced 16B)
        f32x4 a0 = *(const f32x4*)(gA + kt);
        f32x4 a1 = *(const f32x4*)(gA + kt + 4);
        f32x4 a2 = *(const f32x4*)(gA + kt + rowstep);
        f32x4 a3 = *(const f32x4*)(gA + kt + rowstep + 4);
        f32x4 b0 = *(const f32x4*)(gB + kt);
        f32x4 b1 = *(const f32x4*)(gB + kt + 4);
        f32x4 b2 = *(const f32x4*)(gB + kt + rowstep);
        f32x4 b3 = *(const f32x4*)(gB + kt + rowstep + 4);

        __syncthreads();   // previous iter's frag reads done before overwrite

        *(u32x4*)&As[srow * LDA + scol]        = pack8(a0, a1);
        *(u32x4*)&As[(srow + 64) * LDA + scol] = pack8(a2, a3);
        *(u32x4*)&Bs[srow * LDA + scol]        = pack8(b0, b1);
        *(u32x4*)&Bs[(srow + 64) * LDA + scol] = pack8(b2, b3);

        __syncthreads();

        bf16x8 af[4], bf[4];
#pragma unroll
        for (int f = 0; f < 4; f++) {
            af[f] = *(const bf16x8*)&As[(wm * 64 + f * 16 + lcol) * LDA + lquad * 8];
            bf[f] = *(const bf16x8*)&Bs[(wn * 64 + f * 16 + lcol) * LDA + lquad * 8];
        }
#pragma unroll
        for (int mf = 0; mf < 4; mf++)
#pragma unroll
            for (int nf = 0; nf < 4; nf++)
                acc[mf][nf] = __builtin_amdgcn_mfma_f32_16x16x32_bf16(af[mf], bf[nf], acc[mf][nf], 0, 0, 0);
    }

    // Epilogue: C/D layout col = lane&15, row = (lane>>4)*4 + reg  [m89/m91 verified]
    const int colbase = nt * BN + wn * 64;
#pragma unroll
    for (int mf = 0; mf < 4; mf++) {
#pragma unroll
        for (int r = 0; r < 4; r++) {
            const int lrow = wm * 64 + mf * 16 + lquad * 4 + r;
            const int grow = mt * BM + lrow;
            const int t    = tg[lrow];
            float rs = 0.f;
#pragma unroll
            for (int nf = 0; nf < 4; nf++) {
                float v = acc[mf][nf][r];
                rs += __expf(v);
                if (t == colbase + nf * 16 + lcol) tgtlogit[grow] = v;  // unique owner
            }
            rs += __shfl_xor(rs, 1);
            rs += __shfl_xor(rs, 2);
            rs += __shfl_xor(rs, 4);
            rs += __shfl_xor(rs, 8);
            if (lcol == 0) atomicAdd(&sumexp[grow], rs);
        }
    }
}

__global__ __launch_bounds__(256) void finalize(
    const float* __restrict__ sumexp,
    const float* __restrict__ tgtlogit,
    const int*   __restrict__ tgt,
    float* __restrict__ out)
{
    float s = 0.f;
    int   c = 0;
    for (int i = threadIdx.x; i < M_; i += 256) {
        int t = tgt[i];
        if (t != IGNORE_INDEX) {
            s += __logf(sumexp[i]) - tgtlogit[i];
            c++;
        }
    }
#pragma unroll
    for (int o = 32; o; o >>= 1) {
        s += __shfl_down(s, o);
        c += __shfl_down(c, o);
    }
    __shared__ float ss[4];
    __shared__ int   cc[4];
    int w = threadIdx.x >> 6;
    if ((threadIdx.x & 63) == 0) { ss[w] = s; cc[w] = c; }
    __syncthreads();
    if (threadIdx.x == 0) {
        float st = ss[0] + ss[1] + ss[2] + ss[3];
        int   ct = cc[0] + cc[1] + cc[2] + cc[3];
        out[0] = st / (float)ct;
    }
}

extern "C" void kernel_launch(void* const* d_in, const int* in_sizes, int n_in,
                              void* d_out, int out_size, void* d_ws, size_t ws_size,
                              hipStream_t stream) {
    const float* hidden  = (const float*)d_in[0];
    const int*   targets = (const int*)d_in[1];
    const float* W       = (const float*)d_in[2];

    float* sumexp   = (float*)d_ws;       // [M_]
    float* tgtlogit = sumexp + M_;        // [M_]
    float* out      = (float*)d_out;

    init_acc<<<(2 * M_ + 255) / 256, 256, 0, stream>>>(sumexp, 2 * M_);
    gemm_fused<<<dim3(M_ / BM, N_ / BN), 256, 0, stream>>>(hidden, W, targets, sumexp, tgtlogit);
    finalize<<<1, 256, 0, stream>>>(sumexp, tgtlogit, targets, out);
}

// Round 2
// 1579.411 us; speedup vs baseline: 1.3744x; 1.3744x over previous
//
#include <hip/hip_runtime.h>
#include <hip/hip_bf16.h>
#include <stdint.h>

#define IGNORE_INDEX (-100)

constexpr int M_ = 8192;    // B*S tokens
constexpr int K_ = 2048;    // D
constexpr int N_ = 32000;   // V

constexpr int BM = 128, BN = 128, BK = 32;

typedef __attribute__((ext_vector_type(8))) __bf16 bf16x8;
typedef __attribute__((ext_vector_type(4))) float f32x4;
typedef __attribute__((ext_vector_type(4))) unsigned int u32x4;

// ---------- fp32 -> bf16 packing (round-half-up, 1 v_perm per pair) ----------
__device__ __forceinline__ unsigned pack_bf16(float f0, float f1) {
    unsigned u0 = __builtin_bit_cast(unsigned, f0) + 0x8000u;
    unsigned u1 = __builtin_bit_cast(unsigned, f1) + 0x8000u;
    return __builtin_amdgcn_perm(u1, u0, 0x07060302u);
}
__device__ __forceinline__ u32x4 pack8(f32x4 lo, f32x4 hi) {
    u32x4 r;
    r[0] = pack_bf16(lo[0], lo[1]);
    r[1] = pack_bf16(lo[2], lo[3]);
    r[2] = pack_bf16(hi[0], hi[1]);
    r[3] = pack_bf16(hi[2], hi[3]);
    return r;
}

// ---------- async global->LDS, 16B per lane ----------
__device__ __forceinline__ void gll16(const void* g, void* l) {
    __builtin_amdgcn_global_load_lds(
        (const __attribute__((address_space(1))) unsigned int*)g,
        (__attribute__((address_space(3))) unsigned int*)l, 16, 0, 0);
}

__global__ void init_acc(float* p, int n) {
    int i = blockIdx.x * 256 + threadIdx.x;
    if (i < n) p[i] = 0.0f;
}

// convert n8 groups of 8 fp32 -> 8 bf16
__global__ __launch_bounds__(256) void convert_bf16(
    const float* __restrict__ in, __bf16* __restrict__ out, int n8)
{
    int i = blockIdx.x * 256 + threadIdx.x;
    if (i < n8) {
        f32x4 lo = ((const f32x4*)in)[2 * i];
        f32x4 hi = ((const f32x4*)in)[2 * i + 1];
        ((u32x4*)out)[i] = pack8(lo, hi);
    }
}

// ---------------- bf16 GEMM, global_load_lds staging (m97-style) -------------
// A: [M,K] bf16, Wb: [N,K] bf16, both K-contiguous.  LDS tiles [128][32] bf16,
// unpadded (DMA requirement); bank spread via XOR swizzle of the k-group:
// physical col8 = logical col8 ^ ((row>>1)&3), applied at stage (global addr
// permute) and at frag read.  Verified even 8-lanes-per-bank-group spread.
__global__ __launch_bounds__(256) void gemm_bf16(
    const __bf16* __restrict__ A,
    const __bf16* __restrict__ Wb,
    const int*   __restrict__ tgt,
    float* __restrict__ sumexp,
    float* __restrict__ tgtlogit)
{
    __shared__ __bf16 As[BM * BK];
    __shared__ __bf16 Bs[BN * BK];
    __shared__ int    tg[BM];

    const int tid = threadIdx.x;
    const int mt  = blockIdx.x;   // 0..63 fastest -> adjacent blocks share W tile
    const int nt  = blockIdx.y;   // 0..249

    if (tid < BM) tg[tid] = tgt[mt * BM + tid];

    const int wave  = tid >> 6;
    const int lane  = tid & 63;
    const int wm    = wave >> 1;
    const int wn    = wave & 1;
    const int lquad = lane >> 4;
    const int lcol  = lane & 15;

    // --- staging: each wave DMAs 2x16 rows of A and of B (16B/lane) ---
    const int srow0 = wave * 32 + (lane >> 2);
    const int srow1 = srow0 + 16;
    const int scol0 = (((lane & 3) ^ ((srow0 >> 1) & 3))) * 8;
    const int scol1 = (((lane & 3) ^ ((srow1 >> 1) & 3))) * 8;

    const __bf16* gA0 = A  + (size_t)(mt * BM + srow0) * K_ + scol0;
    const __bf16* gA1 = A  + (size_t)(mt * BM + srow1) * K_ + scol1;
    const __bf16* gB0 = Wb + (size_t)(nt * BN + srow0) * K_ + scol0;
    const __bf16* gB1 = Wb + (size_t)(nt * BN + srow1) * K_ + scol1;
    __bf16* lA0 = &As[(wave * 32)      * BK];
    __bf16* lA1 = &As[(wave * 32 + 16) * BK];
    __bf16* lB0 = &Bs[(wave * 32)      * BK];
    __bf16* lB1 = &Bs[(wave * 32 + 16) * BK];

    // --- frag read addresses (swizzle invariant under +16 rows) ---
    const int arow = wm * 64 + lcol;
    const int brow = wn * 64 + lcol;
    const int asw  = (lquad ^ ((arow >> 1) & 3)) * 8;
    const int bsw  = (lquad ^ ((brow >> 1) & 3)) * 8;
    const __bf16* fA = &As[arow * BK + asw];
    const __bf16* fB = &Bs[brow * BK + bsw];

    f32x4 acc[4][4];
#pragma unroll
    for (int i = 0; i < 4; i++)
#pragma unroll
        for (int j = 0; j < 4; j++) acc[i][j] = (f32x4){0.f, 0.f, 0.f, 0.f};

    for (int kt = 0; kt < K_; kt += BK) {
        gll16(gA0 + kt, lA0);
        gll16(gA1 + kt, lA1);
        gll16(gB0 + kt, lB0);
        gll16(gB1 + kt, lB1);
        __syncthreads();   // drains vmcnt(0): DMA done, tiles visible

        bf16x8 af[4], bf[4];
#pragma unroll
        for (int f = 0; f < 4; f++) {
            af[f] = *(const bf16x8*)(fA + f * 16 * BK);
            bf[f] = *(const bf16x8*)(fB + f * 16 * BK);
        }
#pragma unroll
        for (int mf = 0; mf < 4; mf++)
#pragma unroll
            for (int nf = 0; nf < 4; nf++)
                acc[mf][nf] = __builtin_amdgcn_mfma_f32_16x16x32_bf16(af[mf], bf[nf], acc[mf][nf], 0, 0, 0);

        __syncthreads();   // frag reads done before next DMA overwrites
    }

    // --- epilogue: C/D layout col=lane&15, row=(lane>>4)*4+reg ---
    const int colbase = nt * BN + wn * 64;
#pragma unroll
    for (int mf = 0; mf < 4; mf++) {
#pragma unroll
        for (int r = 0; r < 4; r++) {
            const int lrow = wm * 64 + mf * 16 + lquad * 4 + r;
            const int grow = mt * BM + lrow;
            const int t    = tg[lrow];
            float rs = 0.f;
#pragma unroll
            for (int nf = 0; nf < 4; nf++) {
                float v = acc[mf][nf][r];
                rs += __expf(v);
                if (t == colbase + nf * 16 + lcol) tgtlogit[grow] = v;
            }
            rs += __shfl_xor(rs, 1);
            rs += __shfl_xor(rs, 2);
            rs += __shfl_xor(rs, 4);
            rs += __shfl_xor(rs, 8);
            if (lcol == 0) atomicAdd(&sumexp[grow], rs);
        }
    }
}

// ------------- fallback (round-1 kernel) if ws_size too small ----------------
constexpr int LDA = BK + 8;
__global__ __launch_bounds__(256) void gemm_fused_f32(
    const float* __restrict__ A,
    const float* __restrict__ W,
    const int*   __restrict__ tgt,
    float* __restrict__ sumexp,
    float* __restrict__ tgtlogit)
{
    __shared__ __bf16 As[BM * LDA];
    __shared__ __bf16 Bs[BN * LDA];
    __shared__ int    tg[BM];

    const int tid = threadIdx.x;
    const int mt  = blockIdx.x;
    const int nt  = blockIdx.y;
    if (tid < BM) tg[tid] = tgt[mt * BM + tid];

    const int wave = tid >> 6, lane = tid & 63;
    const int wm = wave >> 1, wn = wave & 1;
    const int lquad = lane >> 4, lcol = lane & 15;
    const int srow = tid >> 2, scol = (tid & 3) * 8;

    const float* gA = A + (size_t)(mt * BM + srow) * K_ + scol;
    const float* gB = W + (size_t)(nt * BN + srow) * K_ + scol;
    const size_t rowstep = (size_t)64 * K_;

    f32x4 acc[4][4];
#pragma unroll
    for (int i = 0; i < 4; i++)
#pragma unroll
        for (int j = 0; j < 4; j++) acc[i][j] = (f32x4){0.f, 0.f, 0.f, 0.f};

    for (int kt = 0; kt < K_; kt += BK) {
        f32x4 a0 = *(const f32x4*)(gA + kt);
        f32x4 a1 = *(const f32x4*)(gA + kt + 4);
        f32x4 a2 = *(const f32x4*)(gA + kt + rowstep);
        f32x4 a3 = *(const f32x4*)(gA + kt + rowstep + 4);
        f32x4 b0 = *(const f32x4*)(gB + kt);
        f32x4 b1 = *(const f32x4*)(gB + kt + 4);
        f32x4 b2 = *(const f32x4*)(gB + kt + rowstep);
        f32x4 b3 = *(const f32x4*)(gB + kt + rowstep + 4);
        __syncthreads();
        *(u32x4*)&As[srow * LDA + scol]        = pack8(a0, a1);
        *(u32x4*)&As[(srow + 64) * LDA + scol] = pack8(a2, a3);
        *(u32x4*)&Bs[srow * LDA + scol]        = pack8(b0, b1);
        *(u32x4*)&Bs[(srow + 64) * LDA + scol] = pack8(b2, b3);
        __syncthreads();
        bf16x8 af[4], bf[4];
#pragma unroll
        for (int f = 0; f < 4; f++) {
            af[f] = *(const bf16x8*)&As[(wm * 64 + f * 16 + lcol) * LDA + lquad * 8];
            bf[f] = *(const bf16x8*)&Bs[(wn * 64 + f * 16 + lcol) * LDA + lquad * 8];
        }
#pragma unroll
        for (int mf = 0; mf < 4; mf++)
#pragma unroll
            for (int nf = 0; nf < 4; nf++)
                acc[mf][nf] = __builtin_amdgcn_mfma_f32_16x16x32_bf16(af[mf], bf[nf], acc[mf][nf], 0, 0, 0);
    }
    const int colbase = nt * BN + wn * 64;
#pragma unroll
    for (int mf = 0; mf < 4; mf++) {
#pragma unroll
        for (int r = 0; r < 4; r++) {
            const int lrow = wm * 64 + mf * 16 + lquad * 4 + r;
            const int grow = mt * BM + lrow;
            const int t    = tg[lrow];
            float rs = 0.f;
#pragma unroll
            for (int nf = 0; nf < 4; nf++) {
                float v = acc[mf][nf][r];
                rs += __expf(v);
                if (t == colbase + nf * 16 + lcol) tgtlogit[grow] = v;
            }
            rs += __shfl_xor(rs, 1);
            rs += __shfl_xor(rs, 2);
            rs += __shfl_xor(rs, 4);
            rs += __shfl_xor(rs, 8);
            if (lcol == 0) atomicAdd(&sumexp[grow], rs);
        }
    }
}

__global__ __launch_bounds__(256) void finalize(
    const float* __restrict__ sumexp,
    const float* __restrict__ tgtlogit,
    const int*   __restrict__ tgt,
    float* __restrict__ out)
{
    float s = 0.f;
    int   c = 0;
    for (int i = threadIdx.x; i < M_; i += 256) {
        int t = tgt[i];
        if (t != IGNORE_INDEX) {
            s += __logf(sumexp[i]) - tgtlogit[i];
            c++;
        }
    }
#pragma unroll
    for (int o = 32; o; o >>= 1) {
        s += __shfl_down(s, o);
        c += __shfl_down(c, o);
    }
    __shared__ float ss[4];
    __shared__ int   cc[4];
    int w = threadIdx.x >> 6;
    if ((threadIdx.x & 63) == 0) { ss[w] = s; cc[w] = c; }
    __syncthreads();
    if (threadIdx.x == 0) {
        float st = ss[0] + ss[1] + ss[2] + ss[3];
        int   ct = cc[0] + cc[1] + cc[2] + cc[3];
        out[0] = st / (float)ct;
    }
}

extern "C" void kernel_launch(void* const* d_in, const int* in_sizes, int n_in,
                              void* d_out, int out_size, void* d_ws, size_t ws_size,
                              hipStream_t stream) {
    const float* hidden  = (const float*)d_in[0];
    const int*   targets = (const int*)d_in[1];
    const float* W       = (const float*)d_in[2];

    float* sumexp   = (float*)d_ws;          // [M_] f32
    float* tgtlogit = sumexp + M_;           // [M_] f32
    float* out      = (float*)d_out;

    // bf16 staging copies (16B-aligned offset 65536)
    __bf16* Abf = (__bf16*)((char*)d_ws + 2 * M_ * sizeof(float));
    __bf16* Wbf = Abf + (size_t)M_ * K_;
    const size_t need = 2 * M_ * sizeof(float)
                      + ((size_t)M_ * K_ + (size_t)N_ * K_) * sizeof(__bf16);

    init_acc<<<(2 * M_ + 255) / 256, 256, 0, stream>>>(sumexp, 2 * M_);

    if (ws_size >= need) {
        const int a8 = M_ * K_ / 8;          // 2,097,152
        const int w8 = N_ * K_ / 8;          // 8,192,000
        convert_bf16<<<(a8 + 255) / 256, 256, 0, stream>>>(hidden, Abf, a8);
        convert_bf16<<<(w8 + 255) / 256, 256, 0, stream>>>(W, Wbf, w8);
        gemm_bf16<<<dim3(M_ / BM, N_ / BN), 256, 0, stream>>>(Abf, Wbf, targets, sumexp, tgtlogit);
    } else {
        gemm_fused_f32<<<dim3(M_ / BM, N_ / BN), 256, 0, stream>>>(hidden, W, targets, sumexp, tgtlogit);
    }

    finalize<<<1, 256, 0, stream>>>(sumexp, tgtlogit, targets, out);
}